// Round 8
// baseline (296.657 us; speedup 1.0000x reference)
//
#include <hip/hip_runtime.h>
#include <hip/hip_bf16.h>
#include <hip/hip_fp16.h>

// GCN 2-layer: out = Ahat * relu(Ahat*(X W1)+b1) * W2 + b2
// Round 8: slab-partitioned L2-resident gather.
//  - xs stored slab-major: 8 slabs x [n][F/8] halfs; slab s handled by blocks
//    with blockIdx&7==s -> round-robin XCD dispatch pins each 1.6MB slab table
//    into one XCD's 4MB L2 (heuristic; correctness unaffected if it drifts).
//  - aggregate: thread=(row,slot0..3), 64 rows/block; slot-strided edge walk,
//    conditionals hoisted out (slot0 preloads self row); 16B gathers, unroll 2.
//  - build pipeline + merged bucket_csr unchanged from round 7.

#define N_FEAT_IN 64
#define B2SHIFT 9        // 512 dst nodes per coarse bucket
#define CHUNK 4096       // edges per block in pass A/B

struct alignas(8) half4 { __half2 lo, hi; };
struct alignas(16) half8 { __half2 h[4]; };

// ---- pass A: per-chunk bucket histogram (LDS, no global atomics) ----
__global__ __launch_bounds__(256) void passA_hist(const int* __restrict__ dst,
                                                  int* __restrict__ H, int E) {
    __shared__ int h[256];
    h[threadIdx.x] = 0;
    __syncthreads();
    int base = blockIdx.x * CHUNK;
    int end = min(base + CHUNK, E);
    for (int i = base + threadIdx.x; i < end; i += 256)
        atomicAdd(&h[dst[i] >> B2SHIFT], 1);
    __syncthreads();
    H[blockIdx.x * 256 + threadIdx.x] = h[threadIdx.x];
}

// ---- col_scan_a: one block per column; exclusive scan over NR rows ----
__global__ __launch_bounds__(512) void col_scan_a(int* __restrict__ H,
                                                  int* __restrict__ ctot, int NR) {
    __shared__ int s[512];
    int b = blockIdx.x;
    int t = threadIdx.x;
    int v = (t < NR) ? H[t * 256 + b] : 0;
    s[t] = v;
    __syncthreads();
    for (int off = 1; off < 512; off <<= 1) {
        int a = (t >= off) ? s[t - off] : 0;
        __syncthreads();
        s[t] += a;
        __syncthreads();
    }
    if (t < NR) H[t * 256 + b] = s[t] - v;
    if (t == 511) ctot[b] = s[511];
}

// ---- col_scan_b: scan column totals -> per-bucket bases; row_ptr[n]=E ----
__global__ __launch_bounds__(256) void col_scan_b(const int* __restrict__ ctot,
                                                  int* __restrict__ cbase,
                                                  int* __restrict__ bbase,
                                                  int* __restrict__ row_ptr,
                                                  int NB, int n, int E) {
    __shared__ int s[256];
    int t = threadIdx.x;
    int v = ctot[t];
    s[t] = v;
    __syncthreads();
    for (int off = 1; off < 256; off <<= 1) {
        int a = (t >= off) ? s[t - off] : 0;
        __syncthreads();
        s[t] += a;
        __syncthreads();
    }
    int e = s[t] - v;
    cbase[t] = e;
    if (t < NB) bbase[t] = e;
    if (t == 0) { bbase[NB] = E; row_ptr[n] = E; }
}

// ---- pass B: place packed edges into private per-chunk runs ----
__global__ __launch_bounds__(256) void passB_place(const int* __restrict__ src,
                                                   const int* __restrict__ dst,
                                                   const int* __restrict__ H,
                                                   const int* __restrict__ cbase,
                                                   unsigned* __restrict__ bedges, int E) {
    __shared__ int cur[256];
    cur[threadIdx.x] = H[blockIdx.x * 256 + threadIdx.x] + cbase[threadIdx.x];
    __syncthreads();
    int base = blockIdx.x * CHUNK;
    int end = min(base + CHUNK, E);
    for (int i = base + threadIdx.x; i < end; i += 256) {
        int d = dst[i];
        int p = atomicAdd(&cur[d >> B2SHIFT], 1);  // LDS atomic
        bedges[p] = ((unsigned)src[i] << B2SHIFT) | (unsigned)(d & 511);
    }
}

// ---- merged: per-bucket hist -> local scan -> row_ptr/dinv -> CSR scatter ----
__global__ __launch_bounds__(256) void bucket_csr(const int* __restrict__ bbase,
                                                  const unsigned* __restrict__ bedges,
                                                  int* __restrict__ row_ptr,
                                                  float* __restrict__ dinv,
                                                  int* __restrict__ csr_src, int n) {
    __shared__ int lh[512];
    __shared__ int cur[512];
    int t = threadIdx.x;
    lh[t] = 0;
    lh[t + 256] = 0;
    __syncthreads();
    int b = blockIdx.x;
    int beg = bbase[b], end = bbase[b + 1];
    for (int i = beg + t; i < end; i += 256)
        atomicAdd(&lh[bedges[i] & 511], 1);
    __syncthreads();
    int c0 = lh[t], c1 = lh[t + 256];
    for (int off = 1; off < 512; off <<= 1) {
        int a0 = (t >= off) ? lh[t - off] : 0;
        int a1 = (t + 256 >= off) ? lh[t + 256 - off] : 0;
        __syncthreads();
        lh[t] += a0;
        lh[t + 256] += a1;
        __syncthreads();
    }
#pragma unroll
    for (int k = 0; k < 2; ++k) {
        int local = t + k * 256;
        int d = (b << B2SHIFT) + local;
        int c = (k == 0) ? c0 : c1;
        int excl = beg + lh[local] - c;
        cur[local] = excl;
        if (d < n) {
            row_ptr[d] = excl;
            dinv[d] = rsqrtf((float)c + 1.0f);
        }
    }
    __syncthreads();
    for (int i = beg + t; i < end; i += 256) {
        unsigned v = bedges[i];
        int p = atomicAdd(&cur[v & 511], 1);  // LDS atomic
        csr_src[p] = (int)(v >> B2SHIFT);
    }
}

// ---- GEMM: slab-major fp16 out: xs[slab][n][SW] = half(dinv*(preop(A)*W)) ----
template <int FO, bool RELU_BIAS>
__global__ __launch_bounds__(256) void gemm_rows(const float* __restrict__ A,
                                                 const float* __restrict__ W,
                                                 const float* __restrict__ bias,
                                                 const float* __restrict__ dinv,
                                                 __half* __restrict__ outh, int n) {
    constexpr int K = 64;
    constexpr int CPT = FO / 4;
    constexpr int SW = FO / 8;     // slab width (8 or 4)
    __shared__ float As[64][K + 4];
    __shared__ float Ws[K][FO];

    const int t = threadIdx.x;
    const int r0 = blockIdx.x * 64;

    constexpr int W4 = K * FO / 4;
    for (int i = t; i < W4; i += 256) {
        int k = i / (FO / 4);
        int c4 = (i % (FO / 4)) * 4;
        *(float4*)&Ws[k][c4] = *(const float4*)&W[k * FO + c4];
    }
    for (int i = t; i < 1024; i += 256) {
        int row = i / 16;
        int c4 = (i % 16) * 4;
        int g = r0 + row;
        float4 v = make_float4(0.f, 0.f, 0.f, 0.f);
        if (g < n) {
            v = *(const float4*)&A[(size_t)g * K + c4];
            if (RELU_BIAS) {
                v.x = fmaxf(v.x + bias[c4 + 0], 0.f);
                v.y = fmaxf(v.y + bias[c4 + 1], 0.f);
                v.z = fmaxf(v.z + bias[c4 + 2], 0.f);
                v.w = fmaxf(v.w + bias[c4 + 3], 0.f);
            }
        }
        *(float4*)&As[row][c4] = v;
    }
    __syncthreads();

    const int row = t >> 2;
    const int c0 = (t & 3) * CPT;
    float acc[CPT];
#pragma unroll
    for (int j = 0; j < CPT; ++j) acc[j] = 0.f;

#pragma unroll
    for (int k = 0; k < K; ++k) {
        float xv = As[row][k];
#pragma unroll
        for (int j = 0; j < CPT; ++j) acc[j] = fmaf(xv, Ws[k][c0 + j], acc[j]);
    }

    int g = r0 + row;
    if (g < n) {
        float sc = dinv[g];
#pragma unroll
        for (int j4 = 0; j4 < CPT; j4 += 4) {
            int fb = c0 + j4;
            int slab = fb / SW;
            int p = fb % SW;
            half4 h;
            h.lo = __floats2half2_rn(acc[j4] * sc, acc[j4 + 1] * sc);
            h.hi = __floats2half2_rn(acc[j4 + 2] * sc, acc[j4 + 3] * sc);
            *(half4*)&outh[(size_t)slab * n * SW + (size_t)g * SW + p] = h;
        }
    }
}

// ---- slab-partitioned pull aggregation ----
// blockIdx&7 = slab (XCD round-robin pins slab table in one XCD's L2).
// thread=(row, slot): 64 rows/block, 4 slots walk the edge list strided;
// slot 0 preloads the self row (no conditionals in the hot loop).
template <int F, bool ADD_BIAS>
__global__ __launch_bounds__(256) void aggregate(const int* __restrict__ row_ptr,
                                                 const int* __restrict__ csr_src,
                                                 const float* __restrict__ dinv,
                                                 const __half* __restrict__ xs,
                                                 const float* __restrict__ bias,
                                                 float* __restrict__ out, int n) {
    constexpr int SW = F / 8;      // slab width: 8 (F=64) or 4 (F=32)
    int slab = blockIdx.x & 7;
    int rb = blockIdx.x >> 3;
    int row = rb * 64 + (threadIdx.x >> 2);
    int slot = threadIdx.x & 3;
    if (row >= n) return;          // safe: a row's 4 lanes exit together

    const __half* xsl = xs + (size_t)slab * n * SW;
    int beg = row_ptr[row];
    int end = row_ptr[row + 1];

    float acc[SW];
#pragma unroll
    for (int k = 0; k < SW; ++k) acc[k] = 0.f;

    if (slot == 0) {  // self-loop row, done once
        if constexpr (SW == 8) {
            half8 v = *(const half8*)&xsl[(unsigned)row * 8u];
#pragma unroll
            for (int i = 0; i < 4; ++i) {
                float2 f = __half22float2(v.h[i]);
                acc[2 * i] = f.x;
                acc[2 * i + 1] = f.y;
            }
        } else {
            half4 v = *(const half4*)&xsl[(unsigned)row * 4u];
            float2 lo = __half22float2(v.lo), hi = __half22float2(v.hi);
            acc[0] = lo.x; acc[1] = lo.y; acc[2] = hi.x; acc[3] = hi.y;
        }
    }

#pragma unroll 2
    for (int j = beg + slot; j < end; j += 4) {
        unsigned idx = (unsigned)csr_src[j];
        if constexpr (SW == 8) {
            half8 v = *(const half8*)&xsl[idx * 8u];
#pragma unroll
            for (int i = 0; i < 4; ++i) {
                float2 f = __half22float2(v.h[i]);
                acc[2 * i] += f.x;
                acc[2 * i + 1] += f.y;
            }
        } else {
            half4 v = *(const half4*)&xsl[idx * 4u];
            float2 lo = __half22float2(v.lo), hi = __half22float2(v.hi);
            acc[0] += lo.x; acc[1] += lo.y; acc[2] += hi.x; acc[3] += hi.y;
        }
    }

    // combine the 4 slots (lanes 4r..4r+3)
#pragma unroll
    for (int k = 0; k < SW; ++k) {
        acc[k] += __shfl_xor(acc[k], 1);
        acc[k] += __shfl_xor(acc[k], 2);
    }

    if (slot == 0) {
        float sc = dinv[row];
#pragma unroll
        for (int k = 0; k < SW; k += 4) {
            float4 r;
            r.x = acc[k + 0] * sc;
            r.y = acc[k + 1] * sc;
            r.z = acc[k + 2] * sc;
            r.w = acc[k + 3] * sc;
            if (ADD_BIAS) {
                r.x += bias[slab * SW + k + 0];
                r.y += bias[slab * SW + k + 1];
                r.z += bias[slab * SW + k + 2];
                r.w += bias[slab * SW + k + 3];
            }
            *(float4*)&out[(size_t)row * F + slab * SW + k] = r;
        }
    }
}

extern "C" void kernel_launch(void* const* d_in, const int* in_sizes, int n_in,
                              void* d_out, int out_size, void* d_ws, size_t ws_size,
                              hipStream_t stream) {
    const float* x  = (const float*)d_in[0];   // [n, 64]
    const int*   ei = (const int*)d_in[1];     // [2, E]
    const float* W1 = (const float*)d_in[2];   // [64, 64]
    const float* b1 = (const float*)d_in[3];   // [64]
    const float* W2 = (const float*)d_in[4];   // [64, 32]
    const float* b2 = (const float*)d_in[5];   // [32]
    float* out = (float*)d_out;                // [n, 32]

    const int n = in_sizes[0] / N_FEAT_IN;     // 100000
    const int E = in_sizes[1] / 2;             // 1600000
    const int* srcI = ei;
    const int* dstI = ei + E;

    const int NB = (n + 511) >> B2SHIFT;       // 196 coarse buckets
    const int NR = (E + CHUNK - 1) / CHUNK;    // 391 chunks
    const int NRB = (n + 63) / 64;             // aggregate row-blocks (1563)

    // workspace layout (256B aligned)
    char* ws = (char*)d_ws;
    size_t off = 0;
    auto alloc = [&](size_t bytes) {
        void* p = ws + off;
        off += (bytes + 255) & ~(size_t)255;
        return p;
    };
    float*    dinv    = (float*)alloc((size_t)n * 4);
    int*      row_ptr = (int*)alloc((size_t)(n + 1) * 4);
    int*      bbase   = (int*)alloc((size_t)(NB + 1) * 4);
    int*      ctot    = (int*)alloc((size_t)256 * 4);
    int*      cbase   = (int*)alloc((size_t)256 * 4);
    int*      H       = (int*)alloc((size_t)NR * 256 * 4);   // ~400KB
    unsigned* bedges  = (unsigned*)alloc((size_t)E * 4);
    int*      csr_src = (int*)alloc((size_t)E * 4);
    __half*   xs      = (__half*)alloc((size_t)n * 64 * 2);  // slab-major fp16
    float*    agg1    = (float*)alloc((size_t)n * 64 * 4);

    // 1) atomic-free bucket sort by dst>>9
    passA_hist<<<NR, 256, 0, stream>>>(dstI, H, E);
    col_scan_a<<<256, 512, 0, stream>>>(H, ctot, NR);
    col_scan_b<<<1, 256, 0, stream>>>(ctot, cbase, bbase, row_ptr, NB, n, E);
    passB_place<<<NR, 256, 0, stream>>>(srcI, dstI, H, cbase, bedges, E);

    // 2) merged: row_ptr + dinv + CSR scatter
    bucket_csr<<<NB, 256, 0, stream>>>(bbase, bedges, row_ptr, dinv, csr_src, n);

    // 3) layer 1: xs = slab(half(dinv .* (X W1))); agg1 = dinv .* (gather + self)
    gemm_rows<64, false><<<(n + 63) / 64, 256, 0, stream>>>(x, W1, nullptr, dinv, xs, n);
    aggregate<64, false><<<NRB * 8, 256, 0, stream>>>(row_ptr, csr_src, dinv, xs, nullptr, agg1, n);

    // 4) layer 2: xs2 = slab(half(dinv .* (relu(agg1+b1) W2))); out = ... + b2
    gemm_rows<32, true><<<(n + 63) / 64, 256, 0, stream>>>(agg1, W2, b1, dinv, xs, n);
    aggregate<32, true><<<NRB * 8, 256, 0, stream>>>(row_ptr, csr_src, dinv, xs, b2, out, n);
}

// Round 9
// 261.229 us; speedup vs baseline: 1.1356x; 1.1356x over previous
//
#include <hip/hip_runtime.h>
#include <hip/hip_bf16.h>
#include <hip/hip_fp16.h>

// GCN 2-layer: out = Ahat * relu(Ahat*(X W1)+b1) * W2 + b2
// Round 9: revert to row-major fp16 xs + coalesced full-row gathers (round 6
// was the best gather shape: 2 cache lines per edge). Push memory-level
// parallelism: 2 edge-slots per wave, half2 lanes, 16 edges in flight.
//  - agg64: wave=1 row, 2 slots x 32 half2-lanes, batch 16 (8 loads/slot).
//  - agg32: wave=2 rows, each 2 slots x 16 half2-lanes, batch 8/row.
//  - build: atomic-free bucketed sort + merged bucket_csr (rounds 4-7).

#define N_FEAT_IN 64
#define B2SHIFT 9        // 512 dst nodes per coarse bucket
#define CHUNK 4096       // edges per block in pass A/B

struct alignas(8) half4 { __half2 lo, hi; };

// ---- pass A: per-chunk bucket histogram (LDS, no global atomics) ----
__global__ __launch_bounds__(256) void passA_hist(const int* __restrict__ dst,
                                                  int* __restrict__ H, int E) {
    __shared__ int h[256];
    h[threadIdx.x] = 0;
    __syncthreads();
    int base = blockIdx.x * CHUNK;
    int end = min(base + CHUNK, E);
    for (int i = base + threadIdx.x; i < end; i += 256)
        atomicAdd(&h[dst[i] >> B2SHIFT], 1);
    __syncthreads();
    H[blockIdx.x * 256 + threadIdx.x] = h[threadIdx.x];
}

// ---- col_scan_a: one block per column; exclusive scan over NR rows ----
__global__ __launch_bounds__(512) void col_scan_a(int* __restrict__ H,
                                                  int* __restrict__ ctot, int NR) {
    __shared__ int s[512];
    int b = blockIdx.x;
    int t = threadIdx.x;
    int v = (t < NR) ? H[t * 256 + b] : 0;
    s[t] = v;
    __syncthreads();
    for (int off = 1; off < 512; off <<= 1) {
        int a = (t >= off) ? s[t - off] : 0;
        __syncthreads();
        s[t] += a;
        __syncthreads();
    }
    if (t < NR) H[t * 256 + b] = s[t] - v;
    if (t == 511) ctot[b] = s[511];
}

// ---- col_scan_b: scan column totals -> per-bucket bases; row_ptr[n]=E ----
__global__ __launch_bounds__(256) void col_scan_b(const int* __restrict__ ctot,
                                                  int* __restrict__ cbase,
                                                  int* __restrict__ bbase,
                                                  int* __restrict__ row_ptr,
                                                  int NB, int n, int E) {
    __shared__ int s[256];
    int t = threadIdx.x;
    int v = ctot[t];
    s[t] = v;
    __syncthreads();
    for (int off = 1; off < 256; off <<= 1) {
        int a = (t >= off) ? s[t - off] : 0;
        __syncthreads();
        s[t] += a;
        __syncthreads();
    }
    int e = s[t] - v;
    cbase[t] = e;
    if (t < NB) bbase[t] = e;
    if (t == 0) { bbase[NB] = E; row_ptr[n] = E; }
}

// ---- pass B: place packed edges into private per-chunk runs ----
__global__ __launch_bounds__(256) void passB_place(const int* __restrict__ src,
                                                   const int* __restrict__ dst,
                                                   const int* __restrict__ H,
                                                   const int* __restrict__ cbase,
                                                   unsigned* __restrict__ bedges, int E) {
    __shared__ int cur[256];
    cur[threadIdx.x] = H[blockIdx.x * 256 + threadIdx.x] + cbase[threadIdx.x];
    __syncthreads();
    int base = blockIdx.x * CHUNK;
    int end = min(base + CHUNK, E);
    for (int i = base + threadIdx.x; i < end; i += 256) {
        int d = dst[i];
        int p = atomicAdd(&cur[d >> B2SHIFT], 1);  // LDS atomic
        bedges[p] = ((unsigned)src[i] << B2SHIFT) | (unsigned)(d & 511);
    }
}

// ---- merged: per-bucket hist -> local scan -> row_ptr/dinv -> CSR scatter ----
__global__ __launch_bounds__(256) void bucket_csr(const int* __restrict__ bbase,
                                                  const unsigned* __restrict__ bedges,
                                                  int* __restrict__ row_ptr,
                                                  float* __restrict__ dinv,
                                                  int* __restrict__ csr_src, int n) {
    __shared__ int lh[512];
    __shared__ int cur[512];
    int t = threadIdx.x;
    lh[t] = 0;
    lh[t + 256] = 0;
    __syncthreads();
    int b = blockIdx.x;
    int beg = bbase[b], end = bbase[b + 1];
    for (int i = beg + t; i < end; i += 256)
        atomicAdd(&lh[bedges[i] & 511], 1);
    __syncthreads();
    int c0 = lh[t], c1 = lh[t + 256];
    for (int off = 1; off < 512; off <<= 1) {
        int a0 = (t >= off) ? lh[t - off] : 0;
        int a1 = (t + 256 >= off) ? lh[t + 256 - off] : 0;
        __syncthreads();
        lh[t] += a0;
        lh[t + 256] += a1;
        __syncthreads();
    }
#pragma unroll
    for (int k = 0; k < 2; ++k) {
        int local = t + k * 256;
        int d = (b << B2SHIFT) + local;
        int c = (k == 0) ? c0 : c1;
        int excl = beg + lh[local] - c;
        cur[local] = excl;
        if (d < n) {
            row_ptr[d] = excl;
            dinv[d] = rsqrtf((float)c + 1.0f);
        }
    }
    __syncthreads();
    for (int i = beg + t; i < end; i += 256) {
        unsigned v = bedges[i];
        int p = atomicAdd(&cur[v & 511], 1);  // LDS atomic
        csr_src[p] = (int)(v >> B2SHIFT);
    }
}

// ---- GEMM: outh[n,FO] = half( dinv[row] * (preop(A[n,64]) * W[64,FO]) ) ----
template <int FO, bool RELU_BIAS>
__global__ __launch_bounds__(256) void gemm_rows(const float* __restrict__ A,
                                                 const float* __restrict__ W,
                                                 const float* __restrict__ bias,
                                                 const float* __restrict__ dinv,
                                                 __half* __restrict__ outh, int n) {
    constexpr int K = 64;
    constexpr int CPT = FO / 4;
    __shared__ float As[64][K + 4];
    __shared__ float Ws[K][FO];

    const int t = threadIdx.x;
    const int r0 = blockIdx.x * 64;

    constexpr int W4 = K * FO / 4;
    for (int i = t; i < W4; i += 256) {
        int k = i / (FO / 4);
        int c4 = (i % (FO / 4)) * 4;
        *(float4*)&Ws[k][c4] = *(const float4*)&W[k * FO + c4];
    }
    for (int i = t; i < 1024; i += 256) {
        int row = i / 16;
        int c4 = (i % 16) * 4;
        int g = r0 + row;
        float4 v = make_float4(0.f, 0.f, 0.f, 0.f);
        if (g < n) {
            v = *(const float4*)&A[(size_t)g * K + c4];
            if (RELU_BIAS) {
                v.x = fmaxf(v.x + bias[c4 + 0], 0.f);
                v.y = fmaxf(v.y + bias[c4 + 1], 0.f);
                v.z = fmaxf(v.z + bias[c4 + 2], 0.f);
                v.w = fmaxf(v.w + bias[c4 + 3], 0.f);
            }
        }
        *(float4*)&As[row][c4] = v;
    }
    __syncthreads();

    const int row = t >> 2;
    const int c0 = (t & 3) * CPT;
    float acc[CPT];
#pragma unroll
    for (int j = 0; j < CPT; ++j) acc[j] = 0.f;

#pragma unroll
    for (int k = 0; k < K; ++k) {
        float xv = As[row][k];
#pragma unroll
        for (int j = 0; j < CPT; ++j) acc[j] = fmaf(xv, Ws[k][c0 + j], acc[j]);
    }

    int g = r0 + row;
    if (g < n) {
        float sc = dinv[g];
#pragma unroll
        for (int j4 = 0; j4 < CPT; j4 += 4) {
            half4 h;
            h.lo = __floats2half2_rn(acc[j4] * sc, acc[j4 + 1] * sc);
            h.hi = __floats2half2_rn(acc[j4 + 2] * sc, acc[j4 + 3] * sc);
            *(half4*)&outh[(size_t)g * FO + c0 + j4] = h;
        }
    }
}

// ---- agg64: wave = 1 dst row; 2 edge-slots x 32 half2 feature-lanes ----
// batch 16 edges (8 loads/slot in flight); self-loop hoisted (slot 0).
__global__ __launch_bounds__(256) void aggregate64(const int* __restrict__ row_ptr,
                                                   const int* __restrict__ csr_src,
                                                   const float* __restrict__ dinv,
                                                   const __half2* __restrict__ xs,
                                                   float* __restrict__ out, int n) {
    int d = blockIdx.x * 4 + (threadIdx.x >> 6);
    if (d >= n) return;
    int lane = threadIdx.x & 63;
    int slot = lane >> 5;      // 0/1
    int fc = lane & 31;        // half2 column (features 2fc, 2fc+1)

    int beg = row_ptr[d];
    int end = row_ptr[d + 1];

    float2 a0 = {0.f, 0.f}, a1 = {0.f, 0.f}, a2 = {0.f, 0.f}, a3 = {0.f, 0.f};
    if (slot == 0) {  // self-loop
        float2 v = __half22float2(xs[(unsigned)d * 32u + fc]);
        a0.x = v.x; a0.y = v.y;
    }

    int j = beg;
    for (; j + 16 <= end; j += 16) {
        int jb = j + slot;
        int i0 = csr_src[jb + 0],  i1 = csr_src[jb + 2];
        int i2 = csr_src[jb + 4],  i3 = csr_src[jb + 6];
        int i4 = csr_src[jb + 8],  i5 = csr_src[jb + 10];
        int i6 = csr_src[jb + 12], i7 = csr_src[jb + 14];
        __half2 h0 = xs[(unsigned)i0 * 32u + fc];
        __half2 h1 = xs[(unsigned)i1 * 32u + fc];
        __half2 h2 = xs[(unsigned)i2 * 32u + fc];
        __half2 h3 = xs[(unsigned)i3 * 32u + fc];
        __half2 h4 = xs[(unsigned)i4 * 32u + fc];
        __half2 h5 = xs[(unsigned)i5 * 32u + fc];
        __half2 h6 = xs[(unsigned)i6 * 32u + fc];
        __half2 h7 = xs[(unsigned)i7 * 32u + fc];
        float2 v0 = __half22float2(h0), v1 = __half22float2(h1);
        float2 v2 = __half22float2(h2), v3 = __half22float2(h3);
        float2 v4 = __half22float2(h4), v5 = __half22float2(h5);
        float2 v6 = __half22float2(h6), v7 = __half22float2(h7);
        a0.x += v0.x + v4.x; a0.y += v0.y + v4.y;
        a1.x += v1.x + v5.x; a1.y += v1.y + v5.y;
        a2.x += v2.x + v6.x; a2.y += v2.y + v6.y;
        a3.x += v3.x + v7.x; a3.y += v3.y + v7.y;
    }
    for (j += slot; j < end; j += 2) {
        float2 v = __half22float2(xs[(unsigned)csr_src[j] * 32u + fc]);
        a0.x += v.x; a0.y += v.y;
    }

    float sx = (a0.x + a1.x) + (a2.x + a3.x);
    float sy = (a0.y + a1.y) + (a2.y + a3.y);
    sx += __shfl_xor(sx, 32);
    sy += __shfl_xor(sy, 32);

    if (slot == 0) {
        float sc = dinv[d];
        float2 r = {sx * sc, sy * sc};
        *(float2*)&out[(size_t)d * 64 + 2 * fc] = r;
    }
}

// ---- agg32: wave = 2 rows; each row 2 slots x 16 half2-lanes; batch 8/row ----
__global__ __launch_bounds__(256) void aggregate32(const int* __restrict__ row_ptr,
                                                   const int* __restrict__ csr_src,
                                                   const float* __restrict__ dinv,
                                                   const __half2* __restrict__ xs,
                                                   const float* __restrict__ bias,
                                                   float* __restrict__ out, int n) {
    int d = blockIdx.x * 8 + (threadIdx.x >> 5);
    if (d >= n) return;
    int slot = (threadIdx.x >> 4) & 1;  // 0/1
    int fc = threadIdx.x & 15;          // half2 column (features 2fc, 2fc+1)

    int beg = row_ptr[d];
    int end = row_ptr[d + 1];

    float2 a0 = {0.f, 0.f}, a1 = {0.f, 0.f}, a2 = {0.f, 0.f}, a3 = {0.f, 0.f};
    if (slot == 0) {  // self-loop
        float2 v = __half22float2(xs[(unsigned)d * 16u + fc]);
        a0.x = v.x; a0.y = v.y;
    }

    int j = beg;
    for (; j + 8 <= end; j += 8) {
        int jb = j + slot;
        int i0 = csr_src[jb + 0], i1 = csr_src[jb + 2];
        int i2 = csr_src[jb + 4], i3 = csr_src[jb + 6];
        __half2 h0 = xs[(unsigned)i0 * 16u + fc];
        __half2 h1 = xs[(unsigned)i1 * 16u + fc];
        __half2 h2 = xs[(unsigned)i2 * 16u + fc];
        __half2 h3 = xs[(unsigned)i3 * 16u + fc];
        float2 v0 = __half22float2(h0), v1 = __half22float2(h1);
        float2 v2 = __half22float2(h2), v3 = __half22float2(h3);
        a0.x += v0.x; a0.y += v0.y;
        a1.x += v1.x; a1.y += v1.y;
        a2.x += v2.x; a2.y += v2.y;
        a3.x += v3.x; a3.y += v3.y;
    }
    for (j += slot; j < end; j += 2) {
        float2 v = __half22float2(xs[(unsigned)csr_src[j] * 16u + fc]);
        a0.x += v.x; a0.y += v.y;
    }

    float sx = (a0.x + a1.x) + (a2.x + a3.x);
    float sy = (a0.y + a1.y) + (a2.y + a3.y);
    sx += __shfl_xor(sx, 16);
    sy += __shfl_xor(sy, 16);

    if (slot == 0) {
        float sc = dinv[d];
        float2 r = {sx * sc + bias[2 * fc], sy * sc + bias[2 * fc + 1]};
        *(float2*)&out[(size_t)d * 32 + 2 * fc] = r;
    }
}

extern "C" void kernel_launch(void* const* d_in, const int* in_sizes, int n_in,
                              void* d_out, int out_size, void* d_ws, size_t ws_size,
                              hipStream_t stream) {
    const float* x  = (const float*)d_in[0];   // [n, 64]
    const int*   ei = (const int*)d_in[1];     // [2, E]
    const float* W1 = (const float*)d_in[2];   // [64, 64]
    const float* b1 = (const float*)d_in[3];   // [64]
    const float* W2 = (const float*)d_in[4];   // [64, 32]
    const float* b2 = (const float*)d_in[5];   // [32]
    float* out = (float*)d_out;                // [n, 32]

    const int n = in_sizes[0] / N_FEAT_IN;     // 100000
    const int E = in_sizes[1] / 2;             // 1600000
    const int* srcI = ei;
    const int* dstI = ei + E;

    const int NB = (n + 511) >> B2SHIFT;       // 196 coarse buckets
    const int NR = (E + CHUNK - 1) / CHUNK;    // 391 chunks

    // workspace layout (256B aligned)
    char* ws = (char*)d_ws;
    size_t off = 0;
    auto alloc = [&](size_t bytes) {
        void* p = ws + off;
        off += (bytes + 255) & ~(size_t)255;
        return p;
    };
    float*    dinv    = (float*)alloc((size_t)n * 4);
    int*      row_ptr = (int*)alloc((size_t)(n + 1) * 4);
    int*      bbase   = (int*)alloc((size_t)(NB + 1) * 4);
    int*      ctot    = (int*)alloc((size_t)256 * 4);
    int*      cbase   = (int*)alloc((size_t)256 * 4);
    int*      H       = (int*)alloc((size_t)NR * 256 * 4);   // ~400KB
    unsigned* bedges  = (unsigned*)alloc((size_t)E * 4);
    int*      csr_src = (int*)alloc((size_t)E * 4);
    __half*   xs      = (__half*)alloc((size_t)n * 64 * 2);  // row-major fp16
    float*    agg1    = (float*)alloc((size_t)n * 64 * 4);

    // 1) atomic-free bucket sort by dst>>9
    passA_hist<<<NR, 256, 0, stream>>>(dstI, H, E);
    col_scan_a<<<256, 512, 0, stream>>>(H, ctot, NR);
    col_scan_b<<<1, 256, 0, stream>>>(ctot, cbase, bbase, row_ptr, NB, n, E);
    passB_place<<<NR, 256, 0, stream>>>(srcI, dstI, H, cbase, bedges, E);

    // 2) merged: row_ptr + dinv + CSR scatter
    bucket_csr<<<NB, 256, 0, stream>>>(bbase, bedges, row_ptr, dinv, csr_src, n);

    // 3) layer 1: xs = half(dinv .* (X W1)); agg1 = dinv .* (gather + self)
    gemm_rows<64, false><<<(n + 63) / 64, 256, 0, stream>>>(x, W1, nullptr, dinv, xs, n);
    aggregate64<<<(n + 3) / 4, 256, 0, stream>>>(row_ptr, csr_src, dinv,
                                                 (const __half2*)xs, agg1, n);

    // 4) layer 2: xs2 = half(dinv .* (relu(agg1+b1) W2)); out = ... + b2
    gemm_rows<32, true><<<(n + 63) / 64, 256, 0, stream>>>(agg1, W2, b1, dinv, xs, n);
    aggregate32<<<(n + 7) / 8, 256, 0, stream>>>(row_ptr, csr_src, dinv,
                                                 (const __half2*)xs, b2, out, n);
}

// Round 10
// 243.377 us; speedup vs baseline: 1.2189x; 1.0734x over previous
//
#include <hip/hip_runtime.h>
#include <hip/hip_bf16.h>
#include <hip/hip_fp16.h>

// GCN 2-layer: out = Ahat * relu(Ahat*(X W1)+b1) * W2 + b2
// Round 10: round-6 gather shape (wave=1 row, per-lane 2B loads, one full src
// row per instruction, 8 loads in flight) + TAIL ELIMINATION: zero row at
// index n, clamped indices -> every row runs ceil(deg/8) fully-unrolled
// 8-deep batches (mean deg=16; R9's 16-batch left ~46% of rows serial).
// Build pipeline: atomic-free bucketed counting sort + merged bucket_csr.

#define N_FEAT_IN 64
#define B2SHIFT 9        // 512 dst nodes per coarse bucket
#define CHUNK 4096       // edges per block in pass A/B

struct alignas(8) half4 { __half2 lo, hi; };

// ---- pass A: per-chunk bucket histogram (LDS, no global atomics) ----
__global__ __launch_bounds__(256) void passA_hist(const int* __restrict__ dst,
                                                  int* __restrict__ H, int E) {
    __shared__ int h[256];
    h[threadIdx.x] = 0;
    __syncthreads();
    int base = blockIdx.x * CHUNK;
    int end = min(base + CHUNK, E);
    for (int i = base + threadIdx.x; i < end; i += 256)
        atomicAdd(&h[dst[i] >> B2SHIFT], 1);
    __syncthreads();
    H[blockIdx.x * 256 + threadIdx.x] = h[threadIdx.x];
}

// ---- col_scan_a: one block per column; exclusive scan over NR rows ----
__global__ __launch_bounds__(512) void col_scan_a(int* __restrict__ H,
                                                  int* __restrict__ ctot, int NR) {
    __shared__ int s[512];
    int b = blockIdx.x;
    int t = threadIdx.x;
    int v = (t < NR) ? H[t * 256 + b] : 0;
    s[t] = v;
    __syncthreads();
    for (int off = 1; off < 512; off <<= 1) {
        int a = (t >= off) ? s[t - off] : 0;
        __syncthreads();
        s[t] += a;
        __syncthreads();
    }
    if (t < NR) H[t * 256 + b] = s[t] - v;
    if (t == 511) ctot[b] = s[511];
}

// ---- col_scan_b: scan column totals -> per-bucket bases; row_ptr[n]=E ----
__global__ __launch_bounds__(256) void col_scan_b(const int* __restrict__ ctot,
                                                  int* __restrict__ cbase,
                                                  int* __restrict__ bbase,
                                                  int* __restrict__ row_ptr,
                                                  int NB, int n, int E) {
    __shared__ int s[256];
    int t = threadIdx.x;
    int v = ctot[t];
    s[t] = v;
    __syncthreads();
    for (int off = 1; off < 256; off <<= 1) {
        int a = (t >= off) ? s[t - off] : 0;
        __syncthreads();
        s[t] += a;
        __syncthreads();
    }
    int e = s[t] - v;
    cbase[t] = e;
    if (t < NB) bbase[t] = e;
    if (t == 0) { bbase[NB] = E; row_ptr[n] = E; }
}

// ---- pass B: place packed edges into private per-chunk runs ----
__global__ __launch_bounds__(256) void passB_place(const int* __restrict__ src,
                                                   const int* __restrict__ dst,
                                                   const int* __restrict__ H,
                                                   const int* __restrict__ cbase,
                                                   unsigned* __restrict__ bedges, int E) {
    __shared__ int cur[256];
    cur[threadIdx.x] = H[blockIdx.x * 256 + threadIdx.x] + cbase[threadIdx.x];
    __syncthreads();
    int base = blockIdx.x * CHUNK;
    int end = min(base + CHUNK, E);
    for (int i = base + threadIdx.x; i < end; i += 256) {
        int d = dst[i];
        int p = atomicAdd(&cur[d >> B2SHIFT], 1);  // LDS atomic
        bedges[p] = ((unsigned)src[i] << B2SHIFT) | (unsigned)(d & 511);
    }
}

// ---- merged: per-bucket hist -> local scan -> row_ptr/dinv -> CSR scatter ----
__global__ __launch_bounds__(256) void bucket_csr(const int* __restrict__ bbase,
                                                  const unsigned* __restrict__ bedges,
                                                  int* __restrict__ row_ptr,
                                                  float* __restrict__ dinv,
                                                  int* __restrict__ csr_src, int n) {
    __shared__ int lh[512];
    __shared__ int cur[512];
    int t = threadIdx.x;
    lh[t] = 0;
    lh[t + 256] = 0;
    __syncthreads();
    int b = blockIdx.x;
    int beg = bbase[b], end = bbase[b + 1];
    for (int i = beg + t; i < end; i += 256)
        atomicAdd(&lh[bedges[i] & 511], 1);
    __syncthreads();
    int c0 = lh[t], c1 = lh[t + 256];
    for (int off = 1; off < 512; off <<= 1) {
        int a0 = (t >= off) ? lh[t - off] : 0;
        int a1 = (t + 256 >= off) ? lh[t + 256 - off] : 0;
        __syncthreads();
        lh[t] += a0;
        lh[t + 256] += a1;
        __syncthreads();
    }
#pragma unroll
    for (int k = 0; k < 2; ++k) {
        int local = t + k * 256;
        int d = (b << B2SHIFT) + local;
        int c = (k == 0) ? c0 : c1;
        int excl = beg + lh[local] - c;
        cur[local] = excl;
        if (d < n) {
            row_ptr[d] = excl;
            dinv[d] = rsqrtf((float)c + 1.0f);
        }
    }
    __syncthreads();
    for (int i = beg + t; i < end; i += 256) {
        unsigned v = bedges[i];
        int p = atomicAdd(&cur[v & 511], 1);  // LDS atomic
        csr_src[p] = (int)(v >> B2SHIFT);
    }
}

// ---- GEMM: outh[n,FO] = half( dinv[row] * (preop(A[n,64]) * W[64,FO]) ) ----
// Also zeroes the pad row at index n (block 0).
template <int FO, bool RELU_BIAS>
__global__ __launch_bounds__(256) void gemm_rows(const float* __restrict__ A,
                                                 const float* __restrict__ W,
                                                 const float* __restrict__ bias,
                                                 const float* __restrict__ dinv,
                                                 __half* __restrict__ outh, int n) {
    constexpr int K = 64;
    constexpr int CPT = FO / 4;
    __shared__ float As[64][K + 4];
    __shared__ float Ws[K][FO];

    const int t = threadIdx.x;
    const int r0 = blockIdx.x * 64;

    if (blockIdx.x == 0 && t < FO)  // zero pad row n
        outh[(size_t)n * FO + t] = __float2half(0.f);

    constexpr int W4 = K * FO / 4;
    for (int i = t; i < W4; i += 256) {
        int k = i / (FO / 4);
        int c4 = (i % (FO / 4)) * 4;
        *(float4*)&Ws[k][c4] = *(const float4*)&W[k * FO + c4];
    }
    for (int i = t; i < 1024; i += 256) {
        int row = i / 16;
        int c4 = (i % 16) * 4;
        int g = r0 + row;
        float4 v = make_float4(0.f, 0.f, 0.f, 0.f);
        if (g < n) {
            v = *(const float4*)&A[(size_t)g * K + c4];
            if (RELU_BIAS) {
                v.x = fmaxf(v.x + bias[c4 + 0], 0.f);
                v.y = fmaxf(v.y + bias[c4 + 1], 0.f);
                v.z = fmaxf(v.z + bias[c4 + 2], 0.f);
                v.w = fmaxf(v.w + bias[c4 + 3], 0.f);
            }
        }
        *(float4*)&As[row][c4] = v;
    }
    __syncthreads();

    const int row = t >> 2;
    const int c0 = (t & 3) * CPT;
    float acc[CPT];
#pragma unroll
    for (int j = 0; j < CPT; ++j) acc[j] = 0.f;

#pragma unroll
    for (int k = 0; k < K; ++k) {
        float xv = As[row][k];
#pragma unroll
        for (int j = 0; j < CPT; ++j) acc[j] = fmaf(xv, Ws[k][c0 + j], acc[j]);
    }

    int g = r0 + row;
    if (g < n) {
        float sc = dinv[g];
#pragma unroll
        for (int j4 = 0; j4 < CPT; j4 += 4) {
            half4 h;
            h.lo = __floats2half2_rn(acc[j4] * sc, acc[j4 + 1] * sc);
            h.hi = __floats2half2_rn(acc[j4 + 2] * sc, acc[j4 + 3] * sc);
            *(half4*)&outh[(size_t)g * FO + c0 + j4] = h;
        }
    }
}

// ---- pull aggregation, tail-free: 8 clamped loads per batch, zero row pads ----
// Wave-per-row (F=64) / 2 rows per wave (F=32); lane f loads 2B of each src row.
template <int F, bool ADD_BIAS>
__global__ __launch_bounds__(256) void aggregate(const int* __restrict__ row_ptr,
                                                 const int* __restrict__ csr_src,
                                                 const float* __restrict__ dinv,
                                                 const __half* __restrict__ xs,
                                                 const float* __restrict__ bias,
                                                 float* __restrict__ out, int n) {
    constexpr int NPB = 256 / F;
    constexpr int SH = (F == 64) ? 6 : 5;
    int d = blockIdx.x * NPB + (threadIdx.x >> SH);
    int f = threadIdx.x & (F - 1);
    if (d >= n) return;

    int beg = row_ptr[d];
    int end = row_ptr[d + 1];
    float acc = __half2float(xs[(size_t)d * F + f]);  // self-loop term

    for (int jb = beg; jb < end; jb += 8) {
        int idx[8];
#pragma unroll
        for (int k = 0; k < 8; ++k) {
            int j = jb + k;
            int s = csr_src[min(j, end - 1)];  // safe: loop entered => end>beg
            idx[k] = (j < end) ? s : n;        // n = zero pad row
        }
        float v[8];
#pragma unroll
        for (int k = 0; k < 8; ++k)
            v[k] = __half2float(xs[(size_t)idx[k] * F + f]);
        acc += ((v[0] + v[1]) + (v[2] + v[3])) + ((v[4] + v[5]) + (v[6] + v[7]));
    }

    float r = dinv[d] * acc;
    if (ADD_BIAS) r += bias[f];
    out[(size_t)d * F + f] = r;
}

extern "C" void kernel_launch(void* const* d_in, const int* in_sizes, int n_in,
                              void* d_out, int out_size, void* d_ws, size_t ws_size,
                              hipStream_t stream) {
    const float* x  = (const float*)d_in[0];   // [n, 64]
    const int*   ei = (const int*)d_in[1];     // [2, E]
    const float* W1 = (const float*)d_in[2];   // [64, 64]
    const float* b1 = (const float*)d_in[3];   // [64]
    const float* W2 = (const float*)d_in[4];   // [64, 32]
    const float* b2 = (const float*)d_in[5];   // [32]
    float* out = (float*)d_out;                // [n, 32]

    const int n = in_sizes[0] / N_FEAT_IN;     // 100000
    const int E = in_sizes[1] / 2;             // 1600000
    const int* srcI = ei;
    const int* dstI = ei + E;

    const int NB = (n + 511) >> B2SHIFT;       // 196 coarse buckets
    const int NR = (E + CHUNK - 1) / CHUNK;    // 391 chunks

    // workspace layout (256B aligned)
    char* ws = (char*)d_ws;
    size_t off = 0;
    auto alloc = [&](size_t bytes) {
        void* p = ws + off;
        off += (bytes + 255) & ~(size_t)255;
        return p;
    };
    float*    dinv    = (float*)alloc((size_t)n * 4);
    int*      row_ptr = (int*)alloc((size_t)(n + 1) * 4);
    int*      bbase   = (int*)alloc((size_t)(NB + 1) * 4);
    int*      ctot    = (int*)alloc((size_t)256 * 4);
    int*      cbase   = (int*)alloc((size_t)256 * 4);
    int*      H       = (int*)alloc((size_t)NR * 256 * 4);   // ~400KB
    unsigned* bedges  = (unsigned*)alloc((size_t)E * 4);
    int*      csr_src = (int*)alloc((size_t)E * 4);
    __half*   xs      = (__half*)alloc((size_t)(n + 1) * 64 * 2); // +1 pad row
    float*    agg1    = (float*)alloc((size_t)n * 64 * 4);

    // 1) atomic-free bucket sort by dst>>9
    passA_hist<<<NR, 256, 0, stream>>>(dstI, H, E);
    col_scan_a<<<256, 512, 0, stream>>>(H, ctot, NR);
    col_scan_b<<<1, 256, 0, stream>>>(ctot, cbase, bbase, row_ptr, NB, n, E);
    passB_place<<<NR, 256, 0, stream>>>(srcI, dstI, H, cbase, bedges, E);

    // 2) merged: row_ptr + dinv + CSR scatter
    bucket_csr<<<NB, 256, 0, stream>>>(bbase, bedges, row_ptr, dinv, csr_src, n);

    // 3) layer 1: xs = half(dinv .* (X W1)); agg1 = dinv .* (gather + self)
    gemm_rows<64, false><<<(n + 63) / 64, 256, 0, stream>>>(x, W1, nullptr, dinv, xs, n);
    aggregate<64, false><<<(n + 3) / 4, 256, 0, stream>>>(row_ptr, csr_src, dinv, xs, nullptr, agg1, n);

    // 4) layer 2: xs2 = half(dinv .* (relu(agg1+b1) W2)); out = ... + b2
    gemm_rows<32, true><<<(n + 63) / 64, 256, 0, stream>>>(agg1, W2, b1, dinv, xs, n);
    aggregate<32, true><<<(n + 7) / 8, 256, 0, stream>>>(row_ptr, csr_src, dinv, xs, b2, out, n);
}